// Round 22
// baseline (565.838 us; speedup 1.0000x reference)
//
#include <hip/hip_runtime.h>
#include <hip/hip_bf16.h>

// Shapes (fixed for this problem)
#define B_   16
#define C_   320
#define HW_  1024
#define CO_  256    // conv_out channels
#define NH_  4
#define DKH_ 160
#define QKVC 1344   // 2*640 + 64
#define FCO  1600   // fused conv channels: 256 conv_out + 1344 qkv

using bf16x8 = __attribute__((ext_vector_type(8))) __bf16;
using bf16x4 = __attribute__((ext_vector_type(4))) __bf16;
using f32x4  = __attribute__((ext_vector_type(4))) float;

static __device__ __forceinline__ bf16x8 bzero8() {
  bf16x8 r;
#pragma unroll
  for (int j = 0; j < 8; ++j) r[j] = (__bf16)0.0f;
  return r;
}

// ---------------------------------------------------------------------------
// MERGED per-layer prep: BN+ReLU+transpose (blocks [0,5120)) and weight/rel
// transform (blocks [5120, 5120+ntrans)).  (R20 known-good)
// ---------------------------------------------------------------------------
template <typename TI>
__global__ __launch_bounds__(256)
void prep_layer(const TI* __restrict__ x, const float* __restrict__ g,
                const float* __restrict__ bb, const float* __restrict__ m,
                const float* __restrict__ v, __bf16* __restrict__ y,
                const float* __restrict__ wc, const float* __restrict__ wq,
                __bf16* __restrict__ wt,
                const float* __restrict__ rw, const float* __restrict__ rh,
                __bf16* __restrict__ rwb, __bf16* __restrict__ rhb) {
  __shared__ __bf16 tile[32][33];
  if (blockIdx.x < 5120) {
    int bx = blockIdx.x;
    int tx = threadIdx.x & 31, ty = threadIdx.x >> 5;
    int p0 = (bx & 31) * 32;
    int c0 = ((bx >> 5) % 10) * 32;
    int b = bx / 320;
#pragma unroll
    for (int i = 0; i < 4; ++i) {
      int cl = ty + i * 8;
      int c = c0 + cl;
      int p = p0 + tx;
      float scale = g[c] * rsqrtf(v[c] + 1e-5f);
      float val = ((float)x[((size_t)b * C_ + c) * HW_ + p] - m[c]) * scale + bb[c];
      tile[cl][tx] = (__bf16)fmaxf(val, 0.0f);
    }
    __syncthreads();
#pragma unroll
    for (int i = 0; i < 4; ++i) {
      int pl = ty + i * 8;
      int p = p0 + pl;
      int c = c0 + tx;
      y[((size_t)b * HW_ + p) * C_ + c] = tile[tx][pl];
    }
  } else {
    int idx = (blockIdx.x - 5120) * 256 + threadIdx.x;
    if (idx < FCO * C_) {
      int ci = idx % C_;
      int co = idx / C_;
      const float* src = (co < CO_) ? (wc + ((size_t)co * C_ + ci) * 9)
                                    : (wq + ((size_t)(co - CO_) * C_ + ci) * 9);
#pragma unroll
      for (int t = 0; t < 9; ++t)
        wt[((size_t)t * FCO + co) * C_ + ci] = (__bf16)src[t];
    } else {
      int r = idx - FCO * C_;
      if (r < 63 * DKH_) {
        rwb[r] = (__bf16)rw[r];
        rhb[r] = (__bf16)rh[r];
      }
    }
  }
}

// ---------------------------------------------------------------------------
// FUSED LDS-tiled implicit-GEMM 3x3 conv — EXACT R21 known-good (165 us/layer
// = ~915 TF, at the 2-barrier structure's documented ceiling): 128co x 128p,
// 42.5 KB LDS, 3 blocks/CU, XCD remap, global_load_lds W staging, R15
// reordered per-tap phase, R21 packed q/k epilogue.
// ---------------------------------------------------------------------------
template <typename TO>
__global__ __launch_bounds__(256, 3)
void conv3x3_fused(const __bf16* __restrict__ y, const __bf16* __restrict__ wt,
                   const float* __restrict__ bias_c, const float* __restrict__ bias_q,
                   TO* __restrict__ out, const float* __restrict__ resid,
                   __bf16* __restrict__ qt, __bf16* __restrict__ kt,
                   __bf16* __restrict__ vt) {
  __shared__ __align__(16) char act_s[204 * 128];  // (6*34) slots x 128B
  __shared__ __align__(16) char w_s[128 * 128];    // 128 co x 128B

  int tid = threadIdx.x;
  int lane = tid & 63, wv = tid >> 6;
  int lr = lane & 15, lg = lane >> 4;

  int hw_lin = blockIdx.x + 8 * blockIdx.y + 104 * blockIdx.z;
  int xcd = hw_lin & 7, seq = hw_lin >> 3;
  int yhat = seq >> 4;
  int pair = (seq & 15) * 8 + xcd;
  int xhat = pair & 7, zhat = pair >> 3;

  int b = zhat;
  int co_blk = yhat * 128;
  int h0 = xhat * 4;                 // first image row of this p-tile
  int wco = wv >> 1, wp = wv & 1;

  f32x4 zz = {0.f, 0.f, 0.f, 0.f};
  f32x4 acc[4][4];
#pragma unroll
  for (int m = 0; m < 4; ++m)
#pragma unroll
    for (int n = 0; n < 4; ++n) acc[m][n] = zz;

  int rbase[4], cbase[4];
#pragma unroll
  for (int n = 0; n < 4; ++n) {
    int pb = wp * 64 + n * 16 + lr;      // 0..127 within block
    rbase[n] = (pb >> 5) + 1;            // +1 halo offset
    cbase[n] = (pb & 31) + 1;
  }

  const __bf16* ybase = y + (size_t)b * HW_ * C_;

  int rl8 = lane >> 3;                       // 0..7
  int k8 = lane & 7;
  int swoff = (k8 ^ rl8) * 8;                // pre-swizzled source offset
  const __bf16* wsrc[4];
#pragma unroll
  for (int i = 0; i < 4; ++i) {
    int co = co_blk + i * 32 + wv * 8 + rl8;
    if (co > FCO - 1) co = FCO - 1;          // clamp; epilogue discards OOB co
    wsrc[i] = wt + (size_t)co * C_ + swoff;
  }

  auto stage_W = [&](int tap, int chunk) {
    size_t woff = (size_t)tap * FCO * C_ + chunk * 64;
#pragma unroll
    for (int i = 0; i < 4; ++i)
      __builtin_amdgcn_global_load_lds(
          (const __attribute__((address_space(1))) void*)(wsrc[i] + woff),
          (__attribute__((address_space(3))) void*)(w_s + i * 4096 + wv * 1024),
          16, 0, 0);
  };
  auto stage_act = [&](int chunk) {
    int ci0 = chunk * 64;
    for (int g = tid; g < 1632; g += 256) {
      int gi = g & 7, slot = g >> 3;
      int row = slot / 34, col = slot - row * 34;
      int h = h0 + row - 1, c = col - 1;
      bf16x8 val;
      if ((unsigned)h < 32u && (unsigned)c < 32u)
        val = *(const bf16x8*)(ybase + ((size_t)(h * 32 + c)) * C_ + ci0 + gi * 8);
      else
        val = bzero8();
      *(bf16x8*)(act_s + ((slot * 128 + gi * 16) ^ ((col & 7) << 4))) = val;
    }
  };

  stage_act(0);
  stage_W(0, 0);

  for (int cb = 0; cb < 5; ++cb) {
    for (int tap = 0; tap < 9; ++tap) {
      __syncthreads();   // A: W(t)+act visible (drain covered by prior MFMAs)
      bf16x8 af[2][4];
#pragma unroll
      for (int ks = 0; ks < 2; ++ks)
#pragma unroll
        for (int m = 0; m < 4; ++m) {
          int co_l = wco * 64 + m * 16 + lr;
          af[ks][m] = *(const bf16x8*)(w_s + ((co_l * 128 + ks * 64 + lg * 16) ^ ((co_l & 7) << 4)));
        }
      __syncthreads();   // C: all waves' w_s reads done (lgkm-only drain)
      if (!(cb == 4 && tap == 8))
        stage_W(tap == 8 ? 0 : tap + 1, tap == 8 ? cb + 1 : cb);
      int dh = tap / 3 - 1, dw = tap % 3 - 1;
#pragma unroll
      for (int ks = 0; ks < 2; ++ks) {
        bf16x8 bfv[4];
#pragma unroll
        for (int n = 0; n < 4; ++n) {
          int row = rbase[n] + dh, col = cbase[n] + dw;
          bfv[n] = *(const bf16x8*)(act_s + (((row * 34 + col) * 128 + ks * 64 + lg * 16) ^ ((col & 7) << 4)));
        }
#pragma unroll
        for (int m = 0; m < 4; ++m)
#pragma unroll
          for (int n = 0; n < 4; ++n)
            acc[m][n] = __builtin_amdgcn_mfma_f32_16x16x32_bf16(af[ks][m], bfv[n], acc[m][n], 0, 0, 0);
      }
      if (tap == 8 && cb < 4) {
        __syncthreads();       // all waves' act_s reads done
        stage_act(cb + 1);     // drains at next iteration's barrier A
      }
    }
  }

  const float scaleq = 0.07905694150420949f; // 160^-0.5
  int p_blk = xhat * 128;
#pragma unroll
  for (int m = 0; m < 4; ++m) {
    int co4 = co_blk + wco * 64 + m * 16 + lg * 4;   // aligned to 4
    if (co4 >= FCO) continue;                        // whole quad OOB
    if (co4 < CO_) {
#pragma unroll
      for (int n = 0; n < 4; ++n) {
        int p = p_blk + wp * 64 + n * 16 + lr;
#pragma unroll
        for (int r = 0; r < 4; ++r) {
          int co = co4 + r;
          float val = acc[m][n][r] + bias_c[co];
          size_t o = ((size_t)b * C_ + co) * HW_ + p;
          if (resid) val += resid[o];
          out[o] = (TO)val;
        }
      }
    } else {
      int qco4 = co4 - CO_;
      if (qco4 < 1280) {
        bool isq = qco4 < 640;
        int qk4 = isq ? qco4 : qco4 - 640;
        int nn = qk4 / DKH_, d4 = qk4 - nn * DKH_;   // d4..d4+3 in same head
        __bf16* dst = (isq ? qt : kt) +
                      ((size_t)(b * NH_ + nn) * HW_) * DKH_ + d4;
        float sc = isq ? scaleq : 1.0f;
        float fb[4];
#pragma unroll
        for (int r = 0; r < 4; ++r) fb[r] = bias_q[qco4 + r];
#pragma unroll
        for (int n = 0; n < 4; ++n) {
          int p = p_blk + wp * 64 + n * 16 + lr;
          bf16x4 pk;
#pragma unroll
          for (int r = 0; r < 4; ++r)
            pk[r] = (__bf16)((acc[m][n][r] + fb[r]) * sc);
          *(bf16x4*)(dst + (size_t)p * DKH_) = pk;
        }
      } else {
        int c34 = qco4 - 1280;
#pragma unroll
        for (int n = 0; n < 4; ++n) {
          int p = p_blk + wp * 64 + n * 16 + lr;
#pragma unroll
          for (int r = 0; r < 4; ++r) {
            float val = acc[m][n][r] + bias_q[qco4 + r];
            vt[((size_t)b * 64 + c34 + r) * HW_ + p] = (__bf16)val;
          }
        }
      }
    }
  }
}

// ---------------------------------------------------------------------------
// Fused attention — R19 structure (32 q/block, 8 waves x 128 keys).
// R22 CHANGE: rel-table MFMAs and QK MFMAs run in ONE region before the
// single barrier (rel LDS write happens before QK; barrier moved after QK).
// Removes the early-barrier convoy + staggers K loads; same sync semantics
// (rel write -> barrier -> rel read).  setprio(1) spans the whole region.
// ---------------------------------------------------------------------------
__global__ __launch_bounds__(512, 4)
void attn_kernel(const __bf16* __restrict__ qt, const __bf16* __restrict__ kt,
                 const __bf16* __restrict__ vt, const __bf16* __restrict__ relwb,
                 const __bf16* __restrict__ relhb, __bf16* __restrict__ attn_out) {
  __shared__ float Rw_lds[2][16][66];
  __shared__ float Rh_lds[2][16][66];
  __shared__ __align__(16) __bf16 p_lds[8][16][72];  // per-wave 64-key half
  __shared__ float smax[2][16][8];
  __shared__ float ssum[2][16][8];
  __shared__ float part[8][2][16][16];

  int tid = threadIdx.x;
  int lane = tid & 63, wv = tid >> 6;   // 8 waves
  int lr = lane & 15, lg = lane >> 4;

  int hw_lin = blockIdx.x + 32 * blockIdx.y + 128 * blockIdx.z;
  int xcd = hw_lin & 7, s = hw_lin >> 3;
  int qb = s & 31;
  int gg = (s >> 5) * 8 + xcd;
  int n = gg & 3, b = gg >> 2;

  int p0 = qb * 32;
  const size_t qkbase = ((size_t)(b * NH_ + n)) * HW_ * DKH_;

  bf16x8 qf[2][5];
#pragma unroll
  for (int g = 0; g < 2; ++g)
#pragma unroll
    for (int ks = 0; ks < 5; ++ks)
      qf[g][ks] = *(const bf16x8*)(qt + qkbase + (size_t)(p0 + g * 16 + lr) * DKH_ + ks * 32 + lg * 8);

  f32x4 zz = {0.f, 0.f, 0.f, 0.f};

  __builtin_amdgcn_s_setprio(1);
  // rel-table MFMAs (wave group tg handles tile tg) + LDS write
  {
    int tg = wv >> 2;
    int relpos = (wv & 3) * 16 + lr;
    bool ok = relpos < 63;
    int rp = ok ? relpos : 0;
    f32x4 accw = zz, acch = zz;
#pragma unroll
    for (int ks = 0; ks < 5; ++ks) {
      bf16x8 bw = *(const bf16x8*)(relwb + (size_t)rp * DKH_ + ks * 32 + lg * 8);
      bf16x8 bh = *(const bf16x8*)(relhb + (size_t)rp * DKH_ + ks * 32 + lg * 8);
      if (!ok) { bw = bzero8(); bh = bzero8(); }
      accw = __builtin_amdgcn_mfma_f32_16x16x32_bf16(qf[tg][ks], bw, accw, 0, 0, 0);
      acch = __builtin_amdgcn_mfma_f32_16x16x32_bf16(qf[tg][ks], bh, acch, 0, 0, 0);
    }
#pragma unroll
    for (int r = 0; r < 4; ++r) {
      Rw_lds[tg][lg * 4 + r][relpos] = accw[r];
      Rh_lds[tg][lg * 4 + r][relpos] = acch[r];
    }
  }

  // QK: 128 keys per wave; each kf feeds both q-tiles (same region, no barrier)
  f32x4 acc[2][8];
#pragma unroll
  for (int g = 0; g < 2; ++g)
#pragma unroll
    for (int t = 0; t < 8; ++t) acc[g][t] = zz;

  int key_base = wv * 128;
#pragma unroll
  for (int t = 0; t < 8; ++t) {
    const __bf16* kp = kt + qkbase + (size_t)(key_base + t * 16 + lr) * DKH_ + lg * 8;
#pragma unroll
    for (int ks = 0; ks < 5; ++ks) {
      bf16x8 kf = *(const bf16x8*)(kp + ks * 32);
      acc[0][t] = __builtin_amdgcn_mfma_f32_16x16x32_bf16(qf[0][ks], kf, acc[0][t], 0, 0, 0);
      acc[1][t] = __builtin_amdgcn_mfma_f32_16x16x32_bf16(qf[1][ks], kf, acc[1][t], 0, 0, 0);
    }
  }
  __builtin_amdgcn_s_setprio(0);

  __syncthreads();   // barrier 1 (moved after QK): Rw/Rh ready for rel-add

#pragma unroll
  for (int g = 0; g < 2; ++g)
#pragma unroll
    for (int t = 0; t < 8; ++t) {
      int key = key_base + t * 16 + lr;
      int ky = key & 31, kx = key >> 5;
#pragma unroll
      for (int r = 0; r < 4; ++r) {
        int i = lg * 4 + r;
        int q = p0 + g * 16 + i;
        int yi = q & 31, xi = q >> 5;
        acc[g][t][r] += Rw_lds[g][i][ky - yi + 31] + Rh_lds[g][i][kx - xi + 31];
      }
    }

  float mx[2][4];
#pragma unroll
  for (int g = 0; g < 2; ++g)
#pragma unroll
    for (int r = 0; r < 4; ++r) {
      float m = acc[g][0][r];
#pragma unroll
      for (int t = 1; t < 8; ++t) m = fmaxf(m, acc[g][t][r]);
#pragma unroll
      for (int msk = 1; msk < 16; msk <<= 1)
        m = fmaxf(m, __shfl_xor(m, msk, 64));
      mx[g][r] = m;
    }
  if (lr == 0) {
#pragma unroll
    for (int g = 0; g < 2; ++g)
#pragma unroll
      for (int r = 0; r < 4; ++r) smax[g][lg * 4 + r][wv] = mx[g][r];
  }

  const __bf16* vbase = vt + ((size_t)b * 64 + n * 16 + lr) * HW_ + key_base + lg * 8;
  float sm[2][4] = {{0.f, 0.f, 0.f, 0.f}, {0.f, 0.f, 0.f, 0.f}};
  f32x4 pv[2] = {zz, zz};
#pragma unroll
  for (int half = 0; half < 2; ++half) {
    bf16x8 vfh[2];
#pragma unroll
    for (int ks = 0; ks < 2; ++ks)
      vfh[ks] = *(const bf16x8*)(vbase + (half * 2 + ks) * 32);
#pragma unroll
    for (int g = 0; g < 2; ++g) {
#pragma unroll
      for (int t = half * 4; t < half * 4 + 4; ++t) {
#pragma unroll
        for (int r = 0; r < 4; ++r) {
          float pvv = __expf(acc[g][t][r] - mx[g][r]);
          __bf16 pb = (__bf16)pvv;
          sm[g][r] += (float)pb;          // denominator consistent with bf16 P
          p_lds[wv][lg * 4 + r][(t & 3) * 16 + lr] = pb;
        }
      }
#pragma unroll
      for (int ks = 0; ks < 2; ++ks) {
        bf16x8 pf = *(const bf16x8*)&p_lds[wv][lr][ks * 32 + lg * 8];
        pv[g] = __builtin_amdgcn_mfma_f32_16x16x32_bf16(pf, vfh[ks], pv[g], 0, 0, 0);
      }
    }
  }
#pragma unroll
  for (int g = 0; g < 2; ++g) {
#pragma unroll
    for (int r = 0; r < 4; ++r) {
#pragma unroll
      for (int msk = 1; msk < 16; msk <<= 1)
        sm[g][r] += __shfl_xor(sm[g][r], msk, 64);
    }
  }
  if (lr == 0) {
#pragma unroll
    for (int g = 0; g < 2; ++g)
#pragma unroll
      for (int r = 0; r < 4; ++r) ssum[g][lg * 4 + r][wv] = sm[g][r];
  }
#pragma unroll
  for (int g = 0; g < 2; ++g)
#pragma unroll
    for (int r = 0; r < 4; ++r) part[wv][g][lg * 4 + r][lr] = pv[g][r];
  __syncthreads();   // barrier 2: part/smax/ssum ready

  int g2 = tid >> 8, i = (tid >> 4) & 15, dv = tid & 15;
  float M = smax[g2][i][0];
#pragma unroll
  for (int w = 1; w < 8; ++w) M = fmaxf(M, smax[g2][i][w]);
  float S = 0.f, val = 0.f;
#pragma unroll
  for (int w = 0; w < 8; ++w) {
    float e = __expf(smax[g2][i][w] - M);
    S += ssum[g2][i][w] * e;
    val += part[w][g2][i][dv] * e;
  }
  val /= S;
  int flat = (p0 + g2 * 16 + i) * 16 + dv;
  attn_out[((size_t)b * 64 + n * 16 + (flat >> 10)) * HW_ + (flat & 1023)] = (__bf16)val;
}

// ---------------------------------------------------------------------------
// 1x1 projection: blockIdx.y = 16-channel quarter.
// ---------------------------------------------------------------------------
template <typename TO>
__global__ __launch_bounds__(256)
void proj1x1(const __bf16* __restrict__ attn, const float* __restrict__ w,
             const float* __restrict__ bias, TO* __restrict__ out,
             const float* __restrict__ resid) {
  __shared__ float wl[16][64];
  int tid = threadIdx.x;
  int cq = blockIdx.y, b = blockIdx.z;
  int p = blockIdx.x * 256 + tid;
  for (int i = tid; i < 1024; i += 256)
    wl[i >> 6][i & 63] = w[(cq * 16 + (i >> 6)) * 64 + (i & 63)];
  __syncthreads();
  float in[64];
#pragma unroll
  for (int c = 0; c < 64; ++c) in[c] = (float)attn[((size_t)b * 64 + c) * HW_ + p];
#pragma unroll
  for (int c = 0; c < 16; ++c) {
    int gc = cq * 16 + c;
    float a = bias[gc];
#pragma unroll
    for (int cc = 0; cc < 64; ++cc) a += wl[c][cc] * in[cc];
    size_t o = ((size_t)b * C_ + 256 + gc) * HW_ + p;
    if (resid) a += resid[o];
    out[o] = (TO)a;
  }
}

// ---------------------------------------------------------------------------
extern "C" void kernel_launch(void* const* d_in, const int* in_sizes, int n_in,
                              void* d_out, int out_size, void* d_ws, size_t ws_size,
                              hipStream_t stream) {
  (void)in_sizes; (void)n_in; (void)out_size;
  const float* x = (const float*)d_in[0];
  const float* bn_g[2]   = {(const float*)d_in[1],  (const float*)d_in[5]};
  const float* bn_b[2]   = {(const float*)d_in[2],  (const float*)d_in[6]};
  const float* bn_m[2]   = {(const float*)d_in[3],  (const float*)d_in[7]};
  const float* bn_v[2]   = {(const float*)d_in[4],  (const float*)d_in[8]};
  const float* conv_w[2] = {(const float*)d_in[9],  (const float*)d_in[17]};
  const float* conv_b[2] = {(const float*)d_in[10], (const float*)d_in[18]};
  const float* qkv_w[2]  = {(const float*)d_in[11], (const float*)d_in[19]};
  const float* qkv_b[2]  = {(const float*)d_in[12], (const float*)d_in[20]};
  const float* attn_w[2] = {(const float*)d_in[13], (const float*)d_in[21]};
  const float* attn_b[2] = {(const float*)d_in[14], (const float*)d_in[22]};
  const float* rel_w[2]  = {(const float*)d_in[15], (const float*)d_in[23]};
  const float* rel_h[2]  = {(const float*)d_in[16], (const float*)d_in[24]};

  char* ws = (char*)d_ws;
  size_t off = 0;
  auto take = [&](size_t bytes) {
    char* p = ws + off;
    off += (bytes + 255) & ~(size_t)255;
    return p;
  };
  __bf16* y_nhwc = (__bf16*)take((size_t)B_ * HW_ * C_ * 2);         // 10.5 MB
  __bf16* qt     = (__bf16*)take((size_t)B_ * NH_ * HW_ * DKH_ * 2); // 21 MB
  __bf16* kt2    = (__bf16*)take((size_t)B_ * NH_ * HW_ * DKH_ * 2); // 21 MB
  __bf16* vt     = (__bf16*)take((size_t)B_ * 64 * HW_ * 2);         // 2 MB
  __bf16* attn_c = (__bf16*)take((size_t)B_ * 64 * HW_ * 2);         // 2 MB
  __bf16* l1out  = (__bf16*)take((size_t)B_ * C_ * HW_ * 2);         // 10.5 MB
  __bf16* wt_s   = (__bf16*)take((size_t)9 * FCO * C_ * 2);          // 9.2 MB (fused)
  __bf16* rel_wb = (__bf16*)take((size_t)63 * DKH_ * 2);             // 20 KB
  __bf16* rel_hb = (__bf16*)take((size_t)63 * DKH_ * 2);             // 20 KB
  if (ws_size < off) return;  // diagnostic: finite-error failure => ws too small

  const int ntrans = (FCO * C_ + 63 * DKH_ + 255) / 256;
  const int nprep = 5120 + ntrans;

  for (int l = 0; l < 2; ++l) {
    const float* resid = (l == 0) ? nullptr : x;

    if (l == 0)
      prep_layer<float><<<nprep, 256, 0, stream>>>(
          x, bn_g[l], bn_b[l], bn_m[l], bn_v[l], y_nhwc,
          conv_w[l], qkv_w[l], wt_s, rel_w[l], rel_h[l], rel_wb, rel_hb);
    else
      prep_layer<__bf16><<<nprep, 256, 0, stream>>>(
          l1out, bn_g[l], bn_b[l], bn_m[l], bn_v[l], y_nhwc,
          conv_w[l], qkv_w[l], wt_s, rel_w[l], rel_h[l], rel_wb, rel_hb);

    if (l == 0)
      conv3x3_fused<__bf16><<<dim3(8, 13, 16), 256, 0, stream>>>(
          y_nhwc, wt_s, conv_b[l], qkv_b[l], l1out, nullptr, qt, kt2, vt);
    else
      conv3x3_fused<float><<<dim3(8, 13, 16), 256, 0, stream>>>(
          y_nhwc, wt_s, conv_b[l], qkv_b[l], (float*)d_out, resid, qt, kt2, vt);

    attn_kernel<<<dim3(32, NH_, 16), 512, 0, stream>>>(
        qt, kt2, vt, rel_wb, rel_hb, attn_c);

    if (l == 0)
      proj1x1<__bf16><<<dim3(4, 4, 16), 256, 0, stream>>>(
          attn_c, attn_w[l], attn_b[l], l1out, nullptr);
    else
      proj1x1<float><<<dim3(4, 4, 16), 256, 0, stream>>>(
          attn_c, attn_w[l], attn_b[l], (float*)d_out, resid);
  }
}

// Round 23
// 538.180 us; speedup vs baseline: 1.0514x; 1.0514x over previous
//
#include <hip/hip_runtime.h>
#include <hip/hip_bf16.h>

// Shapes (fixed for this problem)
#define B_   16
#define C_   320
#define HW_  1024
#define CO_  256    // conv_out channels
#define NH_  4
#define DKH_ 160
#define QKVC 1344   // 2*640 + 64
#define FCO  1600   // fused conv channels: 256 conv_out + 1344 qkv

using bf16x8 = __attribute__((ext_vector_type(8))) __bf16;
using bf16x4 = __attribute__((ext_vector_type(4))) __bf16;
using f32x4  = __attribute__((ext_vector_type(4))) float;

static __device__ __forceinline__ bf16x8 bzero8() {
  bf16x8 r;
#pragma unroll
  for (int j = 0; j < 8; ++j) r[j] = (__bf16)0.0f;
  return r;
}

// ---------------------------------------------------------------------------
// MERGED per-layer prep: BN+ReLU+transpose (blocks [0,5120)) and weight/rel
// transform (blocks [5120, 5120+ntrans)).  (R20 known-good)
// ---------------------------------------------------------------------------
template <typename TI>
__global__ __launch_bounds__(256)
void prep_layer(const TI* __restrict__ x, const float* __restrict__ g,
                const float* __restrict__ bb, const float* __restrict__ m,
                const float* __restrict__ v, __bf16* __restrict__ y,
                const float* __restrict__ wc, const float* __restrict__ wq,
                __bf16* __restrict__ wt,
                const float* __restrict__ rw, const float* __restrict__ rh,
                __bf16* __restrict__ rwb, __bf16* __restrict__ rhb) {
  __shared__ __bf16 tile[32][33];
  if (blockIdx.x < 5120) {
    int bx = blockIdx.x;
    int tx = threadIdx.x & 31, ty = threadIdx.x >> 5;
    int p0 = (bx & 31) * 32;
    int c0 = ((bx >> 5) % 10) * 32;
    int b = bx / 320;
#pragma unroll
    for (int i = 0; i < 4; ++i) {
      int cl = ty + i * 8;
      int c = c0 + cl;
      int p = p0 + tx;
      float scale = g[c] * rsqrtf(v[c] + 1e-5f);
      float val = ((float)x[((size_t)b * C_ + c) * HW_ + p] - m[c]) * scale + bb[c];
      tile[cl][tx] = (__bf16)fmaxf(val, 0.0f);
    }
    __syncthreads();
#pragma unroll
    for (int i = 0; i < 4; ++i) {
      int pl = ty + i * 8;
      int p = p0 + pl;
      int c = c0 + tx;
      y[((size_t)b * HW_ + p) * C_ + c] = tile[tx][pl];
    }
  } else {
    int idx = (blockIdx.x - 5120) * 256 + threadIdx.x;
    if (idx < FCO * C_) {
      int ci = idx % C_;
      int co = idx / C_;
      const float* src = (co < CO_) ? (wc + ((size_t)co * C_ + ci) * 9)
                                    : (wq + ((size_t)(co - CO_) * C_ + ci) * 9);
#pragma unroll
      for (int t = 0; t < 9; ++t)
        wt[((size_t)t * FCO + co) * C_ + ci] = (__bf16)src[t];
    } else {
      int r = idx - FCO * C_;
      if (r < 63 * DKH_) {
        rwb[r] = (__bf16)rw[r];
        rhb[r] = (__bf16)rh[r];
      }
    }
  }
}

// ---------------------------------------------------------------------------
// FUSED LDS-tiled implicit-GEMM 3x3 conv — EXACT R21 known-good (165 us/layer
// = ~915 TF, at the 2-barrier structure's documented ceiling): 128co x 128p,
// 42.5 KB LDS, 3 blocks/CU, XCD remap, global_load_lds W staging, R15
// reordered per-tap phase, R21 packed q/k epilogue.
// ---------------------------------------------------------------------------
template <typename TO>
__global__ __launch_bounds__(256, 3)
void conv3x3_fused(const __bf16* __restrict__ y, const __bf16* __restrict__ wt,
                   const float* __restrict__ bias_c, const float* __restrict__ bias_q,
                   TO* __restrict__ out, const float* __restrict__ resid,
                   __bf16* __restrict__ qt, __bf16* __restrict__ kt,
                   __bf16* __restrict__ vt) {
  __shared__ __align__(16) char act_s[204 * 128];  // (6*34) slots x 128B
  __shared__ __align__(16) char w_s[128 * 128];    // 128 co x 128B

  int tid = threadIdx.x;
  int lane = tid & 63, wv = tid >> 6;
  int lr = lane & 15, lg = lane >> 4;

  int hw_lin = blockIdx.x + 8 * blockIdx.y + 104 * blockIdx.z;
  int xcd = hw_lin & 7, seq = hw_lin >> 3;
  int yhat = seq >> 4;
  int pair = (seq & 15) * 8 + xcd;
  int xhat = pair & 7, zhat = pair >> 3;

  int b = zhat;
  int co_blk = yhat * 128;
  int h0 = xhat * 4;                 // first image row of this p-tile
  int wco = wv >> 1, wp = wv & 1;

  f32x4 zz = {0.f, 0.f, 0.f, 0.f};
  f32x4 acc[4][4];
#pragma unroll
  for (int m = 0; m < 4; ++m)
#pragma unroll
    for (int n = 0; n < 4; ++n) acc[m][n] = zz;

  int rbase[4], cbase[4];
#pragma unroll
  for (int n = 0; n < 4; ++n) {
    int pb = wp * 64 + n * 16 + lr;      // 0..127 within block
    rbase[n] = (pb >> 5) + 1;            // +1 halo offset
    cbase[n] = (pb & 31) + 1;
  }

  const __bf16* ybase = y + (size_t)b * HW_ * C_;

  int rl8 = lane >> 3;                       // 0..7
  int k8 = lane & 7;
  int swoff = (k8 ^ rl8) * 8;                // pre-swizzled source offset
  const __bf16* wsrc[4];
#pragma unroll
  for (int i = 0; i < 4; ++i) {
    int co = co_blk + i * 32 + wv * 8 + rl8;
    if (co > FCO - 1) co = FCO - 1;          // clamp; epilogue discards OOB co
    wsrc[i] = wt + (size_t)co * C_ + swoff;
  }

  auto stage_W = [&](int tap, int chunk) {
    size_t woff = (size_t)tap * FCO * C_ + chunk * 64;
#pragma unroll
    for (int i = 0; i < 4; ++i)
      __builtin_amdgcn_global_load_lds(
          (const __attribute__((address_space(1))) void*)(wsrc[i] + woff),
          (__attribute__((address_space(3))) void*)(w_s + i * 4096 + wv * 1024),
          16, 0, 0);
  };
  auto stage_act = [&](int chunk) {
    int ci0 = chunk * 64;
    for (int g = tid; g < 1632; g += 256) {
      int gi = g & 7, slot = g >> 3;
      int row = slot / 34, col = slot - row * 34;
      int h = h0 + row - 1, c = col - 1;
      bf16x8 val;
      if ((unsigned)h < 32u && (unsigned)c < 32u)
        val = *(const bf16x8*)(ybase + ((size_t)(h * 32 + c)) * C_ + ci0 + gi * 8);
      else
        val = bzero8();
      *(bf16x8*)(act_s + ((slot * 128 + gi * 16) ^ ((col & 7) << 4))) = val;
    }
  };

  stage_act(0);
  stage_W(0, 0);

  for (int cb = 0; cb < 5; ++cb) {
    for (int tap = 0; tap < 9; ++tap) {
      __syncthreads();   // A: W(t)+act visible (drain covered by prior MFMAs)
      bf16x8 af[2][4];
#pragma unroll
      for (int ks = 0; ks < 2; ++ks)
#pragma unroll
        for (int m = 0; m < 4; ++m) {
          int co_l = wco * 64 + m * 16 + lr;
          af[ks][m] = *(const bf16x8*)(w_s + ((co_l * 128 + ks * 64 + lg * 16) ^ ((co_l & 7) << 4)));
        }
      __syncthreads();   // C: all waves' w_s reads done (lgkm-only drain)
      if (!(cb == 4 && tap == 8))
        stage_W(tap == 8 ? 0 : tap + 1, tap == 8 ? cb + 1 : cb);
      int dh = tap / 3 - 1, dw = tap % 3 - 1;
#pragma unroll
      for (int ks = 0; ks < 2; ++ks) {
        bf16x8 bfv[4];
#pragma unroll
        for (int n = 0; n < 4; ++n) {
          int row = rbase[n] + dh, col = cbase[n] + dw;
          bfv[n] = *(const bf16x8*)(act_s + (((row * 34 + col) * 128 + ks * 64 + lg * 16) ^ ((col & 7) << 4)));
        }
#pragma unroll
        for (int m = 0; m < 4; ++m)
#pragma unroll
          for (int n = 0; n < 4; ++n)
            acc[m][n] = __builtin_amdgcn_mfma_f32_16x16x32_bf16(af[ks][m], bfv[n], acc[m][n], 0, 0, 0);
      }
      if (tap == 8 && cb < 4) {
        __syncthreads();       // all waves' act_s reads done
        stage_act(cb + 1);     // drains at next iteration's barrier A
      }
    }
  }

  const float scaleq = 0.07905694150420949f; // 160^-0.5
  int p_blk = xhat * 128;
#pragma unroll
  for (int m = 0; m < 4; ++m) {
    int co4 = co_blk + wco * 64 + m * 16 + lg * 4;   // aligned to 4
    if (co4 >= FCO) continue;                        // whole quad OOB
    if (co4 < CO_) {
#pragma unroll
      for (int n = 0; n < 4; ++n) {
        int p = p_blk + wp * 64 + n * 16 + lr;
#pragma unroll
        for (int r = 0; r < 4; ++r) {
          int co = co4 + r;
          float val = acc[m][n][r] + bias_c[co];
          size_t o = ((size_t)b * C_ + co) * HW_ + p;
          if (resid) val += resid[o];
          out[o] = (TO)val;
        }
      }
    } else {
      int qco4 = co4 - CO_;
      if (qco4 < 1280) {
        bool isq = qco4 < 640;
        int qk4 = isq ? qco4 : qco4 - 640;
        int nn = qk4 / DKH_, d4 = qk4 - nn * DKH_;   // d4..d4+3 in same head
        __bf16* dst = (isq ? qt : kt) +
                      ((size_t)(b * NH_ + nn) * HW_) * DKH_ + d4;
        float sc = isq ? scaleq : 1.0f;
        float fb[4];
#pragma unroll
        for (int r = 0; r < 4; ++r) fb[r] = bias_q[qco4 + r];
#pragma unroll
        for (int n = 0; n < 4; ++n) {
          int p = p_blk + wp * 64 + n * 16 + lr;
          bf16x4 pk;
#pragma unroll
          for (int r = 0; r < 4; ++r)
            pk[r] = (__bf16)((acc[m][n][r] + fb[r]) * sc);
          *(bf16x4*)(dst + (size_t)p * DKH_) = pk;
        }
      } else {
        int c34 = qco4 - 1280;
#pragma unroll
        for (int n = 0; n < 4; ++n) {
          int p = p_blk + wp * 64 + n * 16 + lr;
#pragma unroll
          for (int r = 0; r < 4; ++r) {
            float val = acc[m][n][r] + bias_q[qco4 + r];
            vt[((size_t)b * 64 + c34 + r) * HW_ + p] = (__bf16)val;
          }
        }
      }
    }
  }
}

// ---------------------------------------------------------------------------
// Fused attention — EXACT R19/R20/R21 known-good: 32 queries/block, 8 waves
// x 128 keys (VGPR-neutral K-reuse), flash-style local softmax, XCD remap.
// (R22's merged rel+QK region regressed −27 us: the early barrier provides
// phase diversity between waves; reverted.)
// ---------------------------------------------------------------------------
__global__ __launch_bounds__(512, 4)
void attn_kernel(const __bf16* __restrict__ qt, const __bf16* __restrict__ kt,
                 const __bf16* __restrict__ vt, const __bf16* __restrict__ relwb,
                 const __bf16* __restrict__ relhb, __bf16* __restrict__ attn_out) {
  __shared__ float Rw_lds[2][16][66];
  __shared__ float Rh_lds[2][16][66];
  __shared__ __align__(16) __bf16 p_lds[8][16][72];  // per-wave 64-key half
  __shared__ float smax[2][16][8];
  __shared__ float ssum[2][16][8];
  __shared__ float part[8][2][16][16];

  int tid = threadIdx.x;
  int lane = tid & 63, wv = tid >> 6;   // 8 waves
  int lr = lane & 15, lg = lane >> 4;

  int hw_lin = blockIdx.x + 32 * blockIdx.y + 128 * blockIdx.z;
  int xcd = hw_lin & 7, s = hw_lin >> 3;
  int qb = s & 31;
  int gg = (s >> 5) * 8 + xcd;
  int n = gg & 3, b = gg >> 2;

  int p0 = qb * 32;
  const size_t qkbase = ((size_t)(b * NH_ + n)) * HW_ * DKH_;

  bf16x8 qf[2][5];
#pragma unroll
  for (int g = 0; g < 2; ++g)
#pragma unroll
    for (int ks = 0; ks < 5; ++ks)
      qf[g][ks] = *(const bf16x8*)(qt + qkbase + (size_t)(p0 + g * 16 + lr) * DKH_ + ks * 32 + lg * 8);

  f32x4 zz = {0.f, 0.f, 0.f, 0.f};

  {
    int tg = wv >> 2;
    int relpos = (wv & 3) * 16 + lr;
    bool ok = relpos < 63;
    int rp = ok ? relpos : 0;
    f32x4 accw = zz, acch = zz;
#pragma unroll
    for (int ks = 0; ks < 5; ++ks) {
      bf16x8 bw = *(const bf16x8*)(relwb + (size_t)rp * DKH_ + ks * 32 + lg * 8);
      bf16x8 bh = *(const bf16x8*)(relhb + (size_t)rp * DKH_ + ks * 32 + lg * 8);
      if (!ok) { bw = bzero8(); bh = bzero8(); }
      accw = __builtin_amdgcn_mfma_f32_16x16x32_bf16(qf[tg][ks], bw, accw, 0, 0, 0);
      acch = __builtin_amdgcn_mfma_f32_16x16x32_bf16(qf[tg][ks], bh, acch, 0, 0, 0);
    }
#pragma unroll
    for (int r = 0; r < 4; ++r) {
      Rw_lds[tg][lg * 4 + r][relpos] = accw[r];
      Rh_lds[tg][lg * 4 + r][relpos] = acch[r];
    }
  }
  __syncthreads();   // barrier 1: Rw/Rh ready

  f32x4 acc[2][8];
#pragma unroll
  for (int g = 0; g < 2; ++g)
#pragma unroll
    for (int t = 0; t < 8; ++t) acc[g][t] = zz;

  int key_base = wv * 128;
  __builtin_amdgcn_s_setprio(1);
#pragma unroll
  for (int t = 0; t < 8; ++t) {
    const __bf16* kp = kt + qkbase + (size_t)(key_base + t * 16 + lr) * DKH_ + lg * 8;
#pragma unroll
    for (int ks = 0; ks < 5; ++ks) {
      bf16x8 kf = *(const bf16x8*)(kp + ks * 32);
      acc[0][t] = __builtin_amdgcn_mfma_f32_16x16x32_bf16(qf[0][ks], kf, acc[0][t], 0, 0, 0);
      acc[1][t] = __builtin_amdgcn_mfma_f32_16x16x32_bf16(qf[1][ks], kf, acc[1][t], 0, 0, 0);
    }
  }
  __builtin_amdgcn_s_setprio(0);

#pragma unroll
  for (int g = 0; g < 2; ++g)
#pragma unroll
    for (int t = 0; t < 8; ++t) {
      int key = key_base + t * 16 + lr;
      int ky = key & 31, kx = key >> 5;
#pragma unroll
      for (int r = 0; r < 4; ++r) {
        int i = lg * 4 + r;
        int q = p0 + g * 16 + i;
        int yi = q & 31, xi = q >> 5;
        acc[g][t][r] += Rw_lds[g][i][ky - yi + 31] + Rh_lds[g][i][kx - xi + 31];
      }
    }

  float mx[2][4];
#pragma unroll
  for (int g = 0; g < 2; ++g)
#pragma unroll
    for (int r = 0; r < 4; ++r) {
      float m = acc[g][0][r];
#pragma unroll
      for (int t = 1; t < 8; ++t) m = fmaxf(m, acc[g][t][r]);
#pragma unroll
      for (int msk = 1; msk < 16; msk <<= 1)
        m = fmaxf(m, __shfl_xor(m, msk, 64));
      mx[g][r] = m;
    }
  if (lr == 0) {
#pragma unroll
    for (int g = 0; g < 2; ++g)
#pragma unroll
      for (int r = 0; r < 4; ++r) smax[g][lg * 4 + r][wv] = mx[g][r];
  }

  const __bf16* vbase = vt + ((size_t)b * 64 + n * 16 + lr) * HW_ + key_base + lg * 8;
  float sm[2][4] = {{0.f, 0.f, 0.f, 0.f}, {0.f, 0.f, 0.f, 0.f}};
  f32x4 pv[2] = {zz, zz};
#pragma unroll
  for (int half = 0; half < 2; ++half) {
    bf16x8 vfh[2];
#pragma unroll
    for (int ks = 0; ks < 2; ++ks)
      vfh[ks] = *(const bf16x8*)(vbase + (half * 2 + ks) * 32);
#pragma unroll
    for (int g = 0; g < 2; ++g) {
#pragma unroll
      for (int t = half * 4; t < half * 4 + 4; ++t) {
#pragma unroll
        for (int r = 0; r < 4; ++r) {
          float pvv = __expf(acc[g][t][r] - mx[g][r]);
          __bf16 pb = (__bf16)pvv;
          sm[g][r] += (float)pb;          // denominator consistent with bf16 P
          p_lds[wv][lg * 4 + r][(t & 3) * 16 + lr] = pb;
        }
      }
#pragma unroll
      for (int ks = 0; ks < 2; ++ks) {
        bf16x8 pf = *(const bf16x8*)&p_lds[wv][lr][ks * 32 + lg * 8];
        pv[g] = __builtin_amdgcn_mfma_f32_16x16x32_bf16(pf, vfh[ks], pv[g], 0, 0, 0);
      }
    }
  }
#pragma unroll
  for (int g = 0; g < 2; ++g) {
#pragma unroll
    for (int r = 0; r < 4; ++r) {
#pragma unroll
      for (int msk = 1; msk < 16; msk <<= 1)
        sm[g][r] += __shfl_xor(sm[g][r], msk, 64);
    }
  }
  if (lr == 0) {
#pragma unroll
    for (int g = 0; g < 2; ++g)
#pragma unroll
      for (int r = 0; r < 4; ++r) ssum[g][lg * 4 + r][wv] = sm[g][r];
  }
#pragma unroll
  for (int g = 0; g < 2; ++g)
#pragma unroll
    for (int r = 0; r < 4; ++r) part[wv][g][lg * 4 + r][lr] = pv[g][r];
  __syncthreads();   // barrier 2: part/smax/ssum ready

  int g2 = tid >> 8, i = (tid >> 4) & 15, dv = tid & 15;
  float M = smax[g2][i][0];
#pragma unroll
  for (int w = 1; w < 8; ++w) M = fmaxf(M, smax[g2][i][w]);
  float S = 0.f, val = 0.f;
#pragma unroll
  for (int w = 0; w < 8; ++w) {
    float e = __expf(smax[g2][i][w] - M);
    S += ssum[g2][i][w] * e;
    val += part[w][g2][i][dv] * e;
  }
  val /= S;
  int flat = (p0 + g2 * 16 + i) * 16 + dv;
  attn_out[((size_t)b * 64 + n * 16 + (flat >> 10)) * HW_ + (flat & 1023)] = (__bf16)val;
}

// ---------------------------------------------------------------------------
// 1x1 projection: blockIdx.y = 16-channel quarter.
// ---------------------------------------------------------------------------
template <typename TO>
__global__ __launch_bounds__(256)
void proj1x1(const __bf16* __restrict__ attn, const float* __restrict__ w,
             const float* __restrict__ bias, TO* __restrict__ out,
             const float* __restrict__ resid) {
  __shared__ float wl[16][64];
  int tid = threadIdx.x;
  int cq = blockIdx.y, b = blockIdx.z;
  int p = blockIdx.x * 256 + tid;
  for (int i = tid; i < 1024; i += 256)
    wl[i >> 6][i & 63] = w[(cq * 16 + (i >> 6)) * 64 + (i & 63)];
  __syncthreads();
  float in[64];
#pragma unroll
  for (int c = 0; c < 64; ++c) in[c] = (float)attn[((size_t)b * 64 + c) * HW_ + p];
#pragma unroll
  for (int c = 0; c < 16; ++c) {
    int gc = cq * 16 + c;
    float a = bias[gc];
#pragma unroll
    for (int cc = 0; cc < 64; ++cc) a += wl[c][cc] * in[cc];
    size_t o = ((size_t)b * C_ + 256 + gc) * HW_ + p;
    if (resid) a += resid[o];
    out[o] = (TO)a;
  }
}

// ---------------------------------------------------------------------------
extern "C" void kernel_launch(void* const* d_in, const int* in_sizes, int n_in,
                              void* d_out, int out_size, void* d_ws, size_t ws_size,
                              hipStream_t stream) {
  (void)in_sizes; (void)n_in; (void)out_size;
  const float* x = (const float*)d_in[0];
  const float* bn_g[2]   = {(const float*)d_in[1],  (const float*)d_in[5]};
  const float* bn_b[2]   = {(const float*)d_in[2],  (const float*)d_in[6]};
  const float* bn_m[2]   = {(const float*)d_in[3],  (const float*)d_in[7]};
  const float* bn_v[2]   = {(const float*)d_in[4],  (const float*)d_in[8]};
  const float* conv_w[2] = {(const float*)d_in[9],  (const float*)d_in[17]};
  const float* conv_b[2] = {(const float*)d_in[10], (const float*)d_in[18]};
  const float* qkv_w[2]  = {(const float*)d_in[11], (const float*)d_in[19]};
  const float* qkv_b[2]  = {(const float*)d_in[12], (const float*)d_in[20]};
  const float* attn_w[2] = {(const float*)d_in[13], (const float*)d_in[21]};
  const float* attn_b[2] = {(const float*)d_in[14], (const float*)d_in[22]};
  const float* rel_w[2]  = {(const float*)d_in[15], (const float*)d_in[23]};
  const float* rel_h[2]  = {(const float*)d_in[16], (const float*)d_in[24]};

  char* ws = (char*)d_ws;
  size_t off = 0;
  auto take = [&](size_t bytes) {
    char* p = ws + off;
    off += (bytes + 255) & ~(size_t)255;
    return p;
  };
  __bf16* y_nhwc = (__bf16*)take((size_t)B_ * HW_ * C_ * 2);         // 10.5 MB
  __bf16* qt     = (__bf16*)take((size_t)B_ * NH_ * HW_ * DKH_ * 2); // 21 MB
  __bf16* kt2    = (__bf16*)take((size_t)B_ * NH_ * HW_ * DKH_ * 2); // 21 MB
  __bf16* vt     = (__bf16*)take((size_t)B_ * 64 * HW_ * 2);         // 2 MB
  __bf16* attn_c = (__bf16*)take((size_t)B_ * 64 * HW_ * 2);         // 2 MB
  __bf16* l1out  = (__bf16*)take((size_t)B_ * C_ * HW_ * 2);         // 10.5 MB
  __bf16* wt_s   = (__bf16*)take((size_t)9 * FCO * C_ * 2);          // 9.2 MB (fused)
  __bf16* rel_wb = (__bf16*)take((size_t)63 * DKH_ * 2);             // 20 KB
  __bf16* rel_hb = (__bf16*)take((size_t)63 * DKH_ * 2);             // 20 KB
  if (ws_size < off) return;  // diagnostic: finite-error failure => ws too small

  const int ntrans = (FCO * C_ + 63 * DKH_ + 255) / 256;
  const int nprep = 5120 + ntrans;

  for (int l = 0; l < 2; ++l) {
    const float* resid = (l == 0) ? nullptr : x;

    if (l == 0)
      prep_layer<float><<<nprep, 256, 0, stream>>>(
          x, bn_g[l], bn_b[l], bn_m[l], bn_v[l], y_nhwc,
          conv_w[l], qkv_w[l], wt_s, rel_w[l], rel_h[l], rel_wb, rel_hb);
    else
      prep_layer<__bf16><<<nprep, 256, 0, stream>>>(
          l1out, bn_g[l], bn_b[l], bn_m[l], bn_v[l], y_nhwc,
          conv_w[l], qkv_w[l], wt_s, rel_w[l], rel_h[l], rel_wb, rel_hb);

    if (l == 0)
      conv3x3_fused<__bf16><<<dim3(8, 13, 16), 256, 0, stream>>>(
          y_nhwc, wt_s, conv_b[l], qkv_b[l], l1out, nullptr, qt, kt2, vt);
    else
      conv3x3_fused<float><<<dim3(8, 13, 16), 256, 0, stream>>>(
          y_nhwc, wt_s, conv_b[l], qkv_b[l], (float*)d_out, resid, qt, kt2, vt);

    attn_kernel<<<dim3(32, NH_, 16), 512, 0, stream>>>(
        qt, kt2, vt, rel_wb, rel_hb, attn_c);

    if (l == 0)
      proj1x1<__bf16><<<dim3(4, 4, 16), 256, 0, stream>>>(
          attn_c, attn_w[l], attn_b[l], l1out, nullptr);
    else
      proj1x1<float><<<dim3(4, 4, 16), 256, 0, stream>>>(
          attn_c, attn_w[l], attn_b[l], (float*)d_out, resid);
  }
}